// Round 13
// baseline (306.903 us; speedup 1.0000x reference)
//
#include <hip/hip_runtime.h>
#include <hip/hip_bf16.h>
#include <stdint.h>

// ---------------------------------------------------------------------------
// JointAttention (MMDiT-style) on MI355X / gfx950
// R13 = R12 + attn softmax tree-reductions: the 31-deep serial fmax chain and
// 32-deep serial sum chain become depth-5 pairwise trees (v_max3-fusable).
// Register audit: attn is occupancy-bound at 2 waves/SIMD (qf32+sc64+o64
// ~180 combined VGPR+AGPR); 2-blocks/CU LDS plans cannot fit 128 regs -> the
// R9 pipeline is the right structure at this occupancy.
// ---------------------------------------------------------------------------

typedef __attribute__((ext_vector_type(8)))  short bf16x8;   // 8 bf16 (4 VGPRs)
typedef __attribute__((ext_vector_type(4)))  float f32x4;    // 16x16 C/D frag
typedef __attribute__((ext_vector_type(16))) float f32x16;   // 32x32 C/D frag
typedef __attribute__((ext_vector_type(4)))  short s16x4;    // packed 4x bf16

#define NUM_HEADS 12
#define HEAD_DIM  128
#define HIDDEN    1536
#define LTXT      512
#define NIMG      4096
#define STOT      4608      // 512 + 4096 joint sequence
#define QKV3      4608      // 3*12*128 qkv width
// 128^-0.5 * log2(e): scores computed in exp2 domain
#define SCALE_Q2  (0.08838834764831845f * 1.44269504088896340f)
#define DEFER_THR 12.0f     // exp2-domain defer-max threshold (~8.3 nats)

__device__ __forceinline__ float b2f(short s) {
    union { uint32_t u; float f; } c; c.u = ((uint32_t)(uint16_t)s) << 16; return c.f;
}
__device__ __forceinline__ short f2b(float f) {
    union { float f; uint32_t u; } c; c.f = f;
    uint32_t u = c.u + 0x7FFFu + ((c.u >> 16) & 1u);
    return (short)(u >> 16);
}
__device__ __forceinline__ float fexp2(float x) {
#if __has_builtin(__builtin_amdgcn_exp2f)
    return __builtin_amdgcn_exp2f(x);
#else
    return exp2f(x);
#endif
}
__device__ __forceinline__ uint32_t cvt_pk_bf16(float lo, float hi) {
    uint32_t r;
    asm("v_cvt_pk_bf16_f32 %0, %1, %2" : "=v"(r) : "v"(lo), "v"(hi));
    return r;
}
// v_permlane32_swap_b32 a, b:  a' = [a.lo | b.lo], b' = [a.hi | b.hi]
__device__ __forceinline__ void permlane32_swap(uint32_t& a, uint32_t& b) {
    asm("v_permlane32_swap_b32 %0, %1" : "+v"(a), "+v"(b));
}

typedef const void __attribute__((address_space(1)))* gas_p;
typedef void __attribute__((address_space(3)))* las_p;
__device__ __forceinline__ void gload_lds16(const void* g, void* l) {
    __builtin_amdgcn_global_load_lds((gas_p)g, (las_p)l, 16, 0, 0);
}

// pairwise tree reductions over a f32x16 (depth 4, max3-fusable)
__device__ __forceinline__ float tmax16(const f32x16& s) {
    float a0 = fmaxf(s[0], s[1]),  a1 = fmaxf(s[2], s[3]);
    float a2 = fmaxf(s[4], s[5]),  a3 = fmaxf(s[6], s[7]);
    float a4 = fmaxf(s[8], s[9]),  a5 = fmaxf(s[10], s[11]);
    float a6 = fmaxf(s[12], s[13]), a7 = fmaxf(s[14], s[15]);
    float b0 = fmaxf(a0, a1), b1 = fmaxf(a2, a3);
    float b2 = fmaxf(a4, a5), b3 = fmaxf(a6, a7);
    return fmaxf(fmaxf(b0, b1), fmaxf(b2, b3));
}
__device__ __forceinline__ float tsum16(const f32x16& s) {
    float a0 = s[0] + s[1],  a1 = s[2] + s[3];
    float a2 = s[4] + s[5],  a3 = s[6] + s[7];
    float a4 = s[8] + s[9],  a5 = s[10] + s[11];
    float a6 = s[12] + s[13], a7 = s[14] + s[15];
    float b0 = a0 + a1, b1 = a2 + a3, b2 = a4 + a5, b3 = a6 + a7;
    return (b0 + b1) + (b2 + b3);
}

// ---------------------------------------------------------------------------
// fused cast fp32 -> bf16 over 6 contiguous-dst segments, 8 elems/thread.
// ---------------------------------------------------------------------------
__global__ __launch_bounds__(256) void cast6(
    const float* __restrict__ s0, const float* __restrict__ s1,
    const float* __restrict__ s2, const float* __restrict__ s3,
    const float* __restrict__ s4, const float* __restrict__ s5,
    short* __restrict__ dst)
{
    size_t i = (size_t)blockIdx.x * 256 + threadIdx.x;  // units of 8 elems
    const size_t e0 = 98304, e1 = 884736, e2 = 1769472,
                 e3 = 2654208, e4 = 2949120;
    const float* src; size_t base;
    if (i < e2) {
        if (i < e0)      { src = s0; base = 0;  }
        else if (i < e1) { src = s1; base = e0; }
        else             { src = s2; base = e1; }
    } else {
        if (i < e3)      { src = s3; base = e2; }
        else if (i < e4) { src = s4; base = e3; }
        else             { src = s5; base = e4; }
    }
    const float4* p = (const float4*)src + (i - base) * 2;
    float4 a = p[0], b = p[1];
    bf16x8 o;
    o[0] = f2b(a.x); o[1] = f2b(a.y); o[2] = f2b(a.z); o[3] = f2b(a.w);
    o[4] = f2b(b.x); o[5] = f2b(b.y); o[6] = f2b(b.z); o[7] = f2b(b.w);
    *((bf16x8*)dst + i) = o;
}

// ---------------------------------------------------------------------------
// GEMM: C(MxN) = A(MxK) @ Bsel(NxK)^T, Bsel = (bm*128<rowsplit) ? B0 : B1.
// 128x128 tile, BK=32, 2-phase double-buffered staging with counted vmcnt.
// Flat 1D grid with bijective XCD-chunked swizzle.
// ---------------------------------------------------------------------------
template <typename OT>
__global__ __launch_bounds__(256) void gemm_bt2(
    const short* __restrict__ A, const short* __restrict__ B0,
    const short* __restrict__ B1, OT* __restrict__ C,
    int M, int N, int K, int rowsplit, int bnN)
{
    __shared__ __align__(16) short As[2][128 * 32];
    __shared__ __align__(16) short Bs[2][128 * 32];
    const int t    = threadIdx.x;
    const int lane = t & 63, wid = t >> 6;
    const int wr = wid >> 1, wc = wid & 1;
    const int l15 = lane & 15, lk = lane >> 4;

    // XCD swizzle (gridDim.x divisible by 8)
    const int cpx = (int)gridDim.x >> 3;
    const int id  = blockIdx.x;
    const int swz = (id & 7) * cpx + (id >> 3);
    const int bm  = swz / bnN, bn = swz % bnN;

    const short* B = (bm * 128 < rowsplit) ? B0 : B1;
    const int srow = t >> 2, skg = t & 3;
    const short* Ag = A + (size_t)(bm * 128 + srow) * K + skg * 8;
    const short* Bg = B + (size_t)(bn * 128 + srow) * K + skg * 8;
    const size_t rowblk = (size_t)64 * K;

    f32x4 acc[4][4];
    const f32x4 z = {0.f, 0.f, 0.f, 0.f};
#pragma unroll
    for (int i = 0; i < 4; ++i)
#pragma unroll
        for (int j = 0; j < 4; ++j) acc[i][j] = z;

    auto STAGE = [&](int b, int kt) {
        const int k0 = kt * 32;
        gload_lds16(Ag + k0,          &As[b][wid * 512]);
        gload_lds16(Ag + rowblk + k0, &As[b][2048 + wid * 512]);
        gload_lds16(Bg + k0,          &Bs[b][wid * 512]);
        gload_lds16(Bg + rowblk + k0, &Bs[b][2048 + wid * 512]);
    };

    const int NT = K / 32;
    STAGE(0, 0);
    for (int kt = 0; kt < NT; ++kt) {
        const int cur = kt & 1;
        if (kt + 1 < NT) {
            STAGE(cur ^ 1, kt + 1);
            asm volatile("s_waitcnt vmcnt(4)" ::: "memory");
        } else {
            asm volatile("s_waitcnt vmcnt(0)" ::: "memory");
        }
        __builtin_amdgcn_s_barrier();

        bf16x8 af[4], bfr[4];
#pragma unroll
        for (int i = 0; i < 4; ++i)
            af[i] = *(const bf16x8*)&As[cur][(wr * 64 + i * 16 + l15) * 32 + lk * 8];
#pragma unroll
        for (int j = 0; j < 4; ++j)
            bfr[j] = *(const bf16x8*)&Bs[cur][(wc * 64 + j * 16 + l15) * 32 + lk * 8];
        __builtin_amdgcn_s_setprio(1);
#pragma unroll
        for (int i = 0; i < 4; ++i)
#pragma unroll
            for (int j = 0; j < 4; ++j)
                acc[i][j] = __builtin_amdgcn_mfma_f32_16x16x32_bf16(
                    af[i], bfr[j], acc[i][j], 0, 0, 0);
        __builtin_amdgcn_s_setprio(0);

        asm volatile("s_waitcnt lgkmcnt(0)" ::: "memory");
        __builtin_amdgcn_sched_barrier(0);
        __builtin_amdgcn_s_barrier();
    }

    // C/D layout: col = lane&15, row = (lane>>4)*4 + reg
#pragma unroll
    for (int i = 0; i < 4; ++i) {
#pragma unroll
        for (int j = 0; j < 4; ++j) {
            const int row0 = bm * 128 + wr * 64 + i * 16 + lk * 4;
            const int col  = bn * 128 + wc * 64 + j * 16 + l15;
#pragma unroll
            for (int r = 0; r < 4; ++r) {
                float v = acc[i][j][r];
                if constexpr (sizeof(OT) == 2)
                    C[(size_t)(row0 + r) * N + col] = (OT)f2b(v);
                else
                    C[(size_t)(row0 + r) * N + col] = v;
            }
        }
    }
}

// ---------------------------------------------------------------------------
// pack: Y[4608][4608] (txt rows 0..511, img rows 512..) ->
//   Qb[h][s][d] (*SCALE_Q2 incl. log2e, rope for img), Kb[h][s][d] (rope),
//   VTb[h][d][s] (transposed via LDS).
// ---------------------------------------------------------------------------
__global__ __launch_bounds__(256) void pack_qkv(
    const short* __restrict__ Y, const float* __restrict__ rope,
    short* __restrict__ Qb, short* __restrict__ Kb, short* __restrict__ VTb)
{
    const int st = blockIdx.x, h = blockIdx.y, t = threadIdx.x;
    const int s0 = st * 64;
    __shared__ __align__(16) short Vt[128][72];

#pragma unroll
    for (int i = 0; i < 4; ++i) {
        int e  = t + i * 256;
        int sl = e >> 4, dg = e & 15;
        int s  = s0 + sl;
        const short* src = Y + (size_t)s * QKV3;
        bf16x8 q8 = *(const bf16x8*)(src + h * 128 + dg * 8);
        bf16x8 k8 = *(const bf16x8*)(src + (12 + h) * 128 + dg * 8);
        bf16x8 v8 = *(const bf16x8*)(src + (24 + h) * 128 + dg * 8);
        float qf[8], kf[8];
#pragma unroll
        for (int j = 0; j < 8; ++j) { qf[j] = b2f(q8[j]); kf[j] = b2f(k8[j]); }
        if (s >= LTXT) {
            const float* rp = rope + (size_t)(s - LTXT) * 128 + dg * 8;
            float4 r0 = *(const float4*)rp;
            float4 r1 = *(const float4*)(rp + 4);
            float rr[8] = {r0.x, r0.y, r0.z, r0.w, r1.x, r1.y, r1.z, r1.w};
#pragma unroll
            for (int j = 0; j < 4; ++j) {
                float c = rr[2 * j], sn = rr[2 * j + 1];
                float q0 = qf[2 * j], q1 = qf[2 * j + 1];
                qf[2 * j] = q0 * c - q1 * sn; qf[2 * j + 1] = q1 * c + q0 * sn;
                float k0 = kf[2 * j], k1 = kf[2 * j + 1];
                kf[2 * j] = k0 * c - k1 * sn; kf[2 * j + 1] = k1 * c + k0 * sn;
            }
        }
        bf16x8 qo, ko;
#pragma unroll
        for (int j = 0; j < 8; ++j) { qo[j] = f2b(qf[j] * SCALE_Q2); ko[j] = f2b(kf[j]); }
        *(bf16x8*)(Qb + ((size_t)h * STOT + s) * 128 + dg * 8) = qo;
        *(bf16x8*)(Kb + ((size_t)h * STOT + s) * 128 + dg * 8) = ko;
#pragma unroll
        for (int j = 0; j < 8; ++j) Vt[dg * 8 + j][sl] = v8[j];
    }
    __syncthreads();
#pragma unroll
    for (int i = 0; i < 4; ++i) {
        int c = t + i * 256;
        int d = c >> 3, sg = c & 7;
        bf16x8 val = *(const bf16x8*)&Vt[d][sg * 8];
        *(bf16x8*)(VTb + ((size_t)h * 128 + d) * STOT + s0 + sg * 8) = val;
    }
}

// ---------------------------------------------------------------------------
// flash attention, 32x32x16 MFMA, 8 waves x 32 q-rows (QBLK=256), KVBLK=64.
// Per-wave pipelined: QK(j+1) || softmax(j) -> PV(j).
// ---------------------------------------------------------------------------
__global__ __launch_bounds__(512, 2) void attn_fwd(
    const short* __restrict__ Q, const short* __restrict__ Kb,
    const short* __restrict__ VT, short* __restrict__ O)
{
    // XCD swizzle: 216 blocks = 8 XCDs x 27; contiguous (h,qb) per XCD.
    const int id  = blockIdx.x;
    const int swz = (id & 7) * 27 + (id >> 3);
    const int qb  = swz % 18, h = swz / 18;

    const int t = threadIdx.x;
    const int lane = t & 63, wid = t >> 6;
    const int l31 = lane & 31, hi = lane >> 5;
    const int xorb = l31 & 7;

    // [buf][K|V][64*128 shorts]: 4 x (16KB + 16KB) = 128 KB
    __shared__ __align__(16) short KV[4][2][64 * 128];

    // Q B-frags: q = l31, step dk covers k = dk*16 + hi*8 + j
    const short* Qrow = Q + ((size_t)h * STOT + qb * 256 + wid * 32 + l31) * 128;
    bf16x8 qf[8];
#pragma unroll
    for (int dk = 0; dk < 8; ++dk)
        qf[dk] = *(const bf16x8*)(Qrow + dk * 16 + hi * 8);

    f32x16 o[4];
#pragma unroll
    for (int nt = 0; nt < 4; ++nt)
#pragma unroll
        for (int r = 0; r < 16; ++r) o[nt][r] = 0.f;
    float m = -1e30f, den = 0.f;   // per q = l31 (both hi lanes identical)

    const short* Kh = Kb + (size_t)h * STOT * 128;
    const short* Vh = VT + (size_t)h * 128 * STOT;

    // staging sources (chunk i: slot p = t + i*512), per-lane, tile 0 base
    const short* Ksrc[2]; const short* Vsrc[2];
#pragma unroll
    for (int i = 0; i < 2; ++i) {
        int p = t + i * 512;
        int krow = p >> 4, kx = (p & 15) ^ (krow & 7);
        Ksrc[i] = Kh + (size_t)krow * 128 + kx * 8;
        int vrow = p >> 3, vx = (p & 7) ^ (vrow & 7);
        Vsrc[i] = Vh + (size_t)vrow * STOT + vx * 8;
    }

    auto STAGE = [&](int b, int kb) {
#pragma unroll
        for (int i = 0; i < 2; ++i) {
            gload_lds16(Ksrc[i] + (size_t)kb * 8192, &KV[b][0][i * 4096 + wid * 512]);
            gload_lds16(Vsrc[i] + (size_t)kb * 64,   &KV[b][1][i * 4096 + wid * 512]);
        }
    };

    // loop-invariant ds_read byte offsets:
    // K frag (key=l31 row): kaddr[dk] = l31*256 + ((dk*2+hi)^xorb)*16; +8192 for key 32+l31.
    // V frag (d=l31 row): vaddr[s] = l31*128 + ((s*2+hi)^xorb)*16; +nt*4096 for d=nt*32+l31.
    int kaddr[8], vaddr[4];
#pragma unroll
    for (int dk = 0; dk < 8; ++dk)
        kaddr[dk] = l31 * 256 + (((dk * 2 + hi) ^ xorb) << 4);
#pragma unroll
    for (int s = 0; s < 4; ++s)
        vaddr[s] = l31 * 128 + (((s * 2 + hi) ^ xorb) << 4);

    const char* Kb4[4] = { (const char*)&KV[0][0][0], (const char*)&KV[1][0][0],
                           (const char*)&KV[2][0][0], (const char*)&KV[3][0][0] };
    const char* Vb4[4] = { (const char*)&KV[0][1][0], (const char*)&KV[1][1][0],
                           (const char*)&KV[2][1][0], (const char*)&KV[3][1][0] };

    // QK^T for one tile -> (s0, s1) raw scores (keys 0-31, 32-63)
    auto QK = [&](const char* Ksc, f32x16& s0, f32x16& s1) {
#pragma unroll
        for (int r = 0; r < 16; ++r) { s0[r] = 0.f; s1[r] = 0.f; }
        __builtin_amdgcn_s_setprio(1);
#pragma unroll
        for (int dk = 0; dk < 8; ++dk) {
            bf16x8 kf0 = *(const bf16x8*)(Ksc + kaddr[dk]);
            bf16x8 kf1 = *(const bf16x8*)(Ksc + kaddr[dk] + 8192);
            s0 = __builtin_amdgcn_mfma_f32_32x32x16_bf16(kf0, qf[dk], s0, 0, 0, 0);
            s1 = __builtin_amdgcn_mfma_f32_32x32x16_bf16(kf1, qf[dk], s1, 0, 0, 0);
        }
        __builtin_amdgcn_s_setprio(0);
    };

    // softmax (in place on s0/s1) + PV accumulate from Vsc
    auto SMPV = [&](const char* Vsc, f32x16& s0, f32x16& s1) {
        float v = fmaxf(tmax16(s0), tmax16(s1));   // depth-5 tree (max3-fusable)
        v = fmaxf(v, __shfl_xor(v, 32));
        if (__any(v > m + DEFER_THR)) {       // wave-uniform deferred rescale
            float mn = fmaxf(m, v);
            float al = fexp2(m - mn);
            m = mn;
            den *= al;
#pragma unroll
            for (int nt = 0; nt < 4; ++nt)
#pragma unroll
                for (int r = 0; r < 16; ++r) o[nt][r] *= al;
        }
#pragma unroll
        for (int r = 0; r < 16; ++r) s0[r] = fexp2(s0[r] - m);
#pragma unroll
        for (int r = 0; r < 16; ++r) s1[r] = fexp2(s1[r] - m);
        float rs = tsum16(s0) + tsum16(s1);        // depth-5 tree
        rs += __shfl_xor(rs, 32);
        den += rs;

        __builtin_amdgcn_s_setprio(1);
#pragma unroll
        for (int s = 0; s < 4; ++s) {
            const f32x16& pe = (s < 2) ? s0 : s1;   // static (s unrolled)
            const int rb = (s & 1) * 8;
            uint32_t a0 = cvt_pk_bf16(pe[rb + 0], pe[rb + 1]);
            uint32_t a1 = cvt_pk_bf16(pe[rb + 2], pe[rb + 3]);
            uint32_t a2 = cvt_pk_bf16(pe[rb + 4], pe[rb + 5]);
            uint32_t a3 = cvt_pk_bf16(pe[rb + 6], pe[rb + 7]);
            permlane32_swap(a0, a2);
            permlane32_swap(a1, a3);
            union { uint32_t u[4]; bf16x8 v8; } pb;
            pb.u[0] = a0; pb.u[1] = a1; pb.u[2] = a2; pb.u[3] = a3;
#pragma unroll
            for (int nt = 0; nt < 4; ++nt) {
                bf16x8 vf = *(const bf16x8*)(Vsc + vaddr[s] + nt * 4096);
                o[nt] = __builtin_amdgcn_mfma_f32_32x32x16_bf16(vf, pb.v8, o[nt], 0, 0, 0);
            }
        }
        __builtin_amdgcn_s_setprio(0);
    };

    f32x16 scA0, scA1, scB0, scB1;

    // prologue: stage tiles 0,1; QK(0) -> scA
    STAGE(0, 0);
    STAGE(1, 1);
    asm volatile("s_waitcnt vmcnt(4)" ::: "memory");  // own tile-0 loads done
    __builtin_amdgcn_s_barrier();                      // all waves' tile-0 done
    QK(Kb4[0], scA0, scA1);

    // main loop: iter j: STAGE(j+2); vmcnt(4) [drains j+1]; barrier;
    //            QK(j+1) ; SMPV(j).  Period 4 (buf%4) x 2 (sc parity) -> 4.
    for (int jb = 0; jb < 68; jb += 4) {
        STAGE(2, jb + 2);
        asm volatile("s_waitcnt vmcnt(4)" ::: "memory");
        __builtin_amdgcn_s_barrier();
        QK(Kb4[1], scB0, scB1);
        SMPV(Vb4[0], scA0, scA1);

        STAGE(3, jb + 3);
        asm volatile("s_waitcnt vmcnt(4)" ::: "memory");
        __builtin_amdgcn_s_barrier();
        QK(Kb4[2], scA0, scA1);
        SMPV(Vb4[1], scB0, scB1);

        STAGE(0, jb + 4);
        asm volatile("s_waitcnt vmcnt(4)" ::: "memory");
        __builtin_amdgcn_s_barrier();
        QK(Kb4[3], scB0, scB1);
        SMPV(Vb4[2], scA0, scA1);

        STAGE(1, jb + 5);
        asm volatile("s_waitcnt vmcnt(4)" ::: "memory");
        __builtin_amdgcn_s_barrier();
        QK(Kb4[0], scA0, scA1);
        SMPV(Vb4[3], scB0, scB1);
    }
    // tail: j = 68 (stage 70), 69 (stage 71), 70 (no stage), 71 (no QK)
    STAGE(2, 70);
    asm volatile("s_waitcnt vmcnt(4)" ::: "memory");
    __builtin_amdgcn_s_barrier();
    QK(Kb4[1], scB0, scB1);
    SMPV(Vb4[0], scA0, scA1);

    STAGE(3, 71);
    asm volatile("s_waitcnt vmcnt(4)" ::: "memory");
    __builtin_amdgcn_s_barrier();
    QK(Kb4[2], scA0, scA1);
    SMPV(Vb4[1], scB0, scB1);

    asm volatile("s_waitcnt vmcnt(0)" ::: "memory");   // drain STAGE(71)
    __builtin_amdgcn_s_barrier();
    QK(Kb4[3], scB0, scB1);
    SMPV(Vb4[2], scA0, scA1);

    SMPV(Vb4[3], scB0, scB1);                          // j=71: no QK, no barrier

    // epilogue: q = l31; d = nt*32 + g*8 + hi*4 + (0..3) per s16x4 store
    const int qrow = qb * 256 + wid * 32 + l31;
    float inv = 1.0f / den;
    short* Orow = O + (size_t)qrow * HIDDEN + h * 128;
#pragma unroll
    for (int nt = 0; nt < 4; ++nt) {
#pragma unroll
        for (int g = 0; g < 4; ++g) {
            s16x4 w4;
#pragma unroll
            for (int j = 0; j < 4; ++j) w4[j] = f2b(o[nt][g * 4 + j] * inv);
            *(s16x4*)(Orow + nt * 32 + g * 8 + hi * 4) = w4;
        }
    }
}

// ---------------------------------------------------------------------------
extern "C" void kernel_launch(void* const* d_in, const int* in_sizes, int n_in,
                              void* d_out, int out_size, void* d_ws, size_t ws_size,
                              hipStream_t stream)
{
    (void)in_sizes; (void)n_in; (void)out_size; (void)ws_size;
    const float* txt  = (const float*)d_in[0];
    const float* img  = (const float*)d_in[1];
    const float* rope = (const float*)d_in[2];
    const float* Wtq  = (const float*)d_in[3];
    const float* Wiq  = (const float*)d_in[4];
    const float* Wto  = (const float*)d_in[5];
    const float* Wio  = (const float*)d_in[6];
    float* out = (float*)d_out;

    short* w = (short*)d_ws;
    size_t off = 0;
    auto alloc = [&](size_t elems) { short* p = w + off; off += elems; return p; };
    short* txtb = alloc((size_t)LTXT * HIDDEN);   // txtb..Wiob contiguous = cast6 dst
    short* imgb = alloc((size_t)NIMG * HIDDEN);
    short* Wtqb = alloc((size_t)QKV3 * HIDDEN);
    short* Wiqb = alloc((size_t)QKV3 * HIDDEN);
    short* Wtob = alloc((size_t)HIDDEN * HIDDEN);
    short* Wiob = alloc((size_t)HIDDEN * HIDDEN);
    short* Yt   = alloc((size_t)LTXT * QKV3);     // Yt||Yi = Y[4608][4608]
    short* Yi   = alloc((size_t)NIMG * QKV3);
    short* Qb   = alloc((size_t)NUM_HEADS * STOT * HEAD_DIM);
    short* Kb   = alloc((size_t)NUM_HEADS * STOT * HEAD_DIM);
    short* VTb  = alloc((size_t)NUM_HEADS * STOT * HEAD_DIM);
    (void)imgb; (void)Yi;
    short* Ob   = txtb;  // txtb+imgb = 4608*1536, dead after QKV GEMM

    cast6<<<12672, 256, 0, stream>>>(txt, img, Wtq, Wiq, Wto, Wio, txtb);

    // fused QKV projection: rows 0..511 use Wtq, 512.. use Wiq
    gemm_bt2<short><<<1296, 256, 0, stream>>>(
        txtb, Wtqb, Wiqb, Yt, STOT, QKV3, HIDDEN, LTXT, QKV3 / 128);

    pack_qkv<<<dim3(STOT / 64, NUM_HEADS), 256, 0, stream>>>(
        Yt, rope, Qb, Kb, VTb);

    attn_fwd<<<dim3(STOT / 256 * NUM_HEADS), 512, 0, stream>>>(Qb, Kb, VTb, Ob);

    // fused out projection: flat grid 36x12 = 432 = 8*54
    gemm_bt2<float><<<432, 256, 0, stream>>>(
        Ob, Wtob, Wiob, out, STOT, HIDDEN, HIDDEN, LTXT, HIDDEN / 128);
}

// Round 14
// 301.417 us; speedup vs baseline: 1.0182x; 1.0182x over previous
//
#include <hip/hip_runtime.h>
#include <hip/hip_bf16.h>
#include <stdint.h>

// ---------------------------------------------------------------------------
// JointAttention (MMDiT-style) on MI355X / gfx950
// R14 = R12 verbatim (best known: 301.9 us). R13's tree-reduction was
// null-to-negative (softmax chains already hidden by the QK||softmax
// pipeline overlap) -> reverted.
// Pipeline: cast6 -> gemm_bt2(QKV->Y) -> pack(rope+scale+V^T) ->
// attn (32x32 MFMA, 4-buf pipelined, in-reg softmax) -> gemm_bt2(out).
// Standing evidence this is the basin floor:
//  - attn: register-occupancy-bound (2 waves/SIMD; ~180 live regs/wave),
//    structural 4-way LDS b128 conflict, all alternatives measured worse
//    (R4/R5/R8/R9/R13 deltas).
//  - GEMMs: 2-phase-structure ceiling; 256^2/8-phase (R10) and dataflow
//    restructure (R11) both regressed at these grid shapes.
//  - cast/pack: HBM-BW-bound, vectorized.
// ---------------------------------------------------------------------------

typedef __attribute__((ext_vector_type(8)))  short bf16x8;   // 8 bf16 (4 VGPRs)
typedef __attribute__((ext_vector_type(4)))  float f32x4;    // 16x16 C/D frag
typedef __attribute__((ext_vector_type(16))) float f32x16;   // 32x32 C/D frag
typedef __attribute__((ext_vector_type(4)))  short s16x4;    // packed 4x bf16

#define NUM_HEADS 12
#define HEAD_DIM  128
#define HIDDEN    1536
#define LTXT      512
#define NIMG      4096
#define STOT      4608      // 512 + 4096 joint sequence
#define QKV3      4608      // 3*12*128 qkv width
// 128^-0.5 * log2(e): scores computed in exp2 domain
#define SCALE_Q2  (0.08838834764831845f * 1.44269504088896340f)
#define DEFER_THR 12.0f     // exp2-domain defer-max threshold (~8.3 nats)

__device__ __forceinline__ float b2f(short s) {
    union { uint32_t u; float f; } c; c.u = ((uint32_t)(uint16_t)s) << 16; return c.f;
}
__device__ __forceinline__ short f2b(float f) {
    union { float f; uint32_t u; } c; c.f = f;
    uint32_t u = c.u + 0x7FFFu + ((c.u >> 16) & 1u);
    return (short)(u >> 16);
}
__device__ __forceinline__ float fexp2(float x) {
#if __has_builtin(__builtin_amdgcn_exp2f)
    return __builtin_amdgcn_exp2f(x);
#else
    return exp2f(x);
#endif
}
__device__ __forceinline__ uint32_t cvt_pk_bf16(float lo, float hi) {
    uint32_t r;
    asm("v_cvt_pk_bf16_f32 %0, %1, %2" : "=v"(r) : "v"(lo), "v"(hi));
    return r;
}
// v_permlane32_swap_b32 a, b:  a' = [a.lo | b.lo], b' = [a.hi | b.hi]
__device__ __forceinline__ void permlane32_swap(uint32_t& a, uint32_t& b) {
    asm("v_permlane32_swap_b32 %0, %1" : "+v"(a), "+v"(b));
}

typedef const void __attribute__((address_space(1)))* gas_p;
typedef void __attribute__((address_space(3)))* las_p;
__device__ __forceinline__ void gload_lds16(const void* g, void* l) {
    __builtin_amdgcn_global_load_lds((gas_p)g, (las_p)l, 16, 0, 0);
}

// ---------------------------------------------------------------------------
// fused cast fp32 -> bf16 over 6 contiguous-dst segments, 8 elems/thread.
// ---------------------------------------------------------------------------
__global__ __launch_bounds__(256) void cast6(
    const float* __restrict__ s0, const float* __restrict__ s1,
    const float* __restrict__ s2, const float* __restrict__ s3,
    const float* __restrict__ s4, const float* __restrict__ s5,
    short* __restrict__ dst)
{
    size_t i = (size_t)blockIdx.x * 256 + threadIdx.x;  // units of 8 elems
    const size_t e0 = 98304, e1 = 884736, e2 = 1769472,
                 e3 = 2654208, e4 = 2949120;
    const float* src; size_t base;
    if (i < e2) {
        if (i < e0)      { src = s0; base = 0;  }
        else if (i < e1) { src = s1; base = e0; }
        else             { src = s2; base = e1; }
    } else {
        if (i < e3)      { src = s3; base = e2; }
        else if (i < e4) { src = s4; base = e3; }
        else             { src = s5; base = e4; }
    }
    const float4* p = (const float4*)src + (i - base) * 2;
    float4 a = p[0], b = p[1];
    bf16x8 o;
    o[0] = f2b(a.x); o[1] = f2b(a.y); o[2] = f2b(a.z); o[3] = f2b(a.w);
    o[4] = f2b(b.x); o[5] = f2b(b.y); o[6] = f2b(b.z); o[7] = f2b(b.w);
    *((bf16x8*)dst + i) = o;
}

// ---------------------------------------------------------------------------
// GEMM: C(MxN) = A(MxK) @ Bsel(NxK)^T, Bsel = (bm*128<rowsplit) ? B0 : B1.
// 128x128 tile, BK=32, 2-phase double-buffered staging with counted vmcnt.
// Flat 1D grid with bijective XCD-chunked swizzle.
// ---------------------------------------------------------------------------
template <typename OT>
__global__ __launch_bounds__(256) void gemm_bt2(
    const short* __restrict__ A, const short* __restrict__ B0,
    const short* __restrict__ B1, OT* __restrict__ C,
    int M, int N, int K, int rowsplit, int bnN)
{
    __shared__ __align__(16) short As[2][128 * 32];
    __shared__ __align__(16) short Bs[2][128 * 32];
    const int t    = threadIdx.x;
    const int lane = t & 63, wid = t >> 6;
    const int wr = wid >> 1, wc = wid & 1;
    const int l15 = lane & 15, lk = lane >> 4;

    // XCD swizzle (gridDim.x divisible by 8)
    const int cpx = (int)gridDim.x >> 3;
    const int id  = blockIdx.x;
    const int swz = (id & 7) * cpx + (id >> 3);
    const int bm  = swz / bnN, bn = swz % bnN;

    const short* B = (bm * 128 < rowsplit) ? B0 : B1;
    const int srow = t >> 2, skg = t & 3;
    const short* Ag = A + (size_t)(bm * 128 + srow) * K + skg * 8;
    const short* Bg = B + (size_t)(bn * 128 + srow) * K + skg * 8;
    const size_t rowblk = (size_t)64 * K;

    f32x4 acc[4][4];
    const f32x4 z = {0.f, 0.f, 0.f, 0.f};
#pragma unroll
    for (int i = 0; i < 4; ++i)
#pragma unroll
        for (int j = 0; j < 4; ++j) acc[i][j] = z;

    auto STAGE = [&](int b, int kt) {
        const int k0 = kt * 32;
        gload_lds16(Ag + k0,          &As[b][wid * 512]);
        gload_lds16(Ag + rowblk + k0, &As[b][2048 + wid * 512]);
        gload_lds16(Bg + k0,          &Bs[b][wid * 512]);
        gload_lds16(Bg + rowblk + k0, &Bs[b][2048 + wid * 512]);
    };

    const int NT = K / 32;
    STAGE(0, 0);
    for (int kt = 0; kt < NT; ++kt) {
        const int cur = kt & 1;
        if (kt + 1 < NT) {
            STAGE(cur ^ 1, kt + 1);
            asm volatile("s_waitcnt vmcnt(4)" ::: "memory");
        } else {
            asm volatile("s_waitcnt vmcnt(0)" ::: "memory");
        }
        __builtin_amdgcn_s_barrier();

        bf16x8 af[4], bfr[4];
#pragma unroll
        for (int i = 0; i < 4; ++i)
            af[i] = *(const bf16x8*)&As[cur][(wr * 64 + i * 16 + l15) * 32 + lk * 8];
#pragma unroll
        for (int j = 0; j < 4; ++j)
            bfr[j] = *(const bf16x8*)&Bs[cur][(wc * 64 + j * 16 + l15) * 32 + lk * 8];
        __builtin_amdgcn_s_setprio(1);
#pragma unroll
        for (int i = 0; i < 4; ++i)
#pragma unroll
            for (int j = 0; j < 4; ++j)
                acc[i][j] = __builtin_amdgcn_mfma_f32_16x16x32_bf16(
                    af[i], bfr[j], acc[i][j], 0, 0, 0);
        __builtin_amdgcn_s_setprio(0);

        asm volatile("s_waitcnt lgkmcnt(0)" ::: "memory");
        __builtin_amdgcn_sched_barrier(0);
        __builtin_amdgcn_s_barrier();
    }

    // C/D layout: col = lane&15, row = (lane>>4)*4 + reg
#pragma unroll
    for (int i = 0; i < 4; ++i) {
#pragma unroll
        for (int j = 0; j < 4; ++j) {
            const int row0 = bm * 128 + wr * 64 + i * 16 + lk * 4;
            const int col  = bn * 128 + wc * 64 + j * 16 + l15;
#pragma unroll
            for (int r = 0; r < 4; ++r) {
                float v = acc[i][j][r];
                if constexpr (sizeof(OT) == 2)
                    C[(size_t)(row0 + r) * N + col] = (OT)f2b(v);
                else
                    C[(size_t)(row0 + r) * N + col] = v;
            }
        }
    }
}

// ---------------------------------------------------------------------------
// pack: Y[4608][4608] (txt rows 0..511, img rows 512..) ->
//   Qb[h][s][d] (*SCALE_Q2 incl. log2e, rope for img), Kb[h][s][d] (rope),
//   VTb[h][d][s] (transposed via LDS).
// ---------------------------------------------------------------------------
__global__ __launch_bounds__(256) void pack_qkv(
    const short* __restrict__ Y, const float* __restrict__ rope,
    short* __restrict__ Qb, short* __restrict__ Kb, short* __restrict__ VTb)
{
    const int st = blockIdx.x, h = blockIdx.y, t = threadIdx.x;
    const int s0 = st * 64;
    __shared__ __align__(16) short Vt[128][72];

#pragma unroll
    for (int i = 0; i < 4; ++i) {
        int e  = t + i * 256;
        int sl = e >> 4, dg = e & 15;
        int s  = s0 + sl;
        const short* src = Y + (size_t)s * QKV3;
        bf16x8 q8 = *(const bf16x8*)(src + h * 128 + dg * 8);
        bf16x8 k8 = *(const bf16x8*)(src + (12 + h) * 128 + dg * 8);
        bf16x8 v8 = *(const bf16x8*)(src + (24 + h) * 128 + dg * 8);
        float qf[8], kf[8];
#pragma unroll
        for (int j = 0; j < 8; ++j) { qf[j] = b2f(q8[j]); kf[j] = b2f(k8[j]); }
        if (s >= LTXT) {
            const float* rp = rope + (size_t)(s - LTXT) * 128 + dg * 8;
            float4 r0 = *(const float4*)rp;
            float4 r1 = *(const float4*)(rp + 4);
            float rr[8] = {r0.x, r0.y, r0.z, r0.w, r1.x, r1.y, r1.z, r1.w};
#pragma unroll
            for (int j = 0; j < 4; ++j) {
                float c = rr[2 * j], sn = rr[2 * j + 1];
                float q0 = qf[2 * j], q1 = qf[2 * j + 1];
                qf[2 * j] = q0 * c - q1 * sn; qf[2 * j + 1] = q1 * c + q0 * sn;
                float k0 = kf[2 * j], k1 = kf[2 * j + 1];
                kf[2 * j] = k0 * c - k1 * sn; kf[2 * j + 1] = k1 * c + k0 * sn;
            }
        }
        bf16x8 qo, ko;
#pragma unroll
        for (int j = 0; j < 8; ++j) { qo[j] = f2b(qf[j] * SCALE_Q2); ko[j] = f2b(kf[j]); }
        *(bf16x8*)(Qb + ((size_t)h * STOT + s) * 128 + dg * 8) = qo;
        *(bf16x8*)(Kb + ((size_t)h * STOT + s) * 128 + dg * 8) = ko;
#pragma unroll
        for (int j = 0; j < 8; ++j) Vt[dg * 8 + j][sl] = v8[j];
    }
    __syncthreads();
#pragma unroll
    for (int i = 0; i < 4; ++i) {
        int c = t + i * 256;
        int d = c >> 3, sg = c & 7;
        bf16x8 val = *(const bf16x8*)&Vt[d][sg * 8];
        *(bf16x8*)(VTb + ((size_t)h * 128 + d) * STOT + s0 + sg * 8) = val;
    }
}

// ---------------------------------------------------------------------------
// flash attention, 32x32x16 MFMA, 8 waves x 32 q-rows (QBLK=256), KVBLK=64.
// Per-wave pipelined: QK(j+1) || softmax(j) -> PV(j).
// ---------------------------------------------------------------------------
__global__ __launch_bounds__(512, 2) void attn_fwd(
    const short* __restrict__ Q, const short* __restrict__ Kb,
    const short* __restrict__ VT, short* __restrict__ O)
{
    // XCD swizzle: 216 blocks = 8 XCDs x 27; contiguous (h,qb) per XCD.
    const int id  = blockIdx.x;
    const int swz = (id & 7) * 27 + (id >> 3);
    const int qb  = swz % 18, h = swz / 18;

    const int t = threadIdx.x;
    const int lane = t & 63, wid = t >> 6;
    const int l31 = lane & 31, hi = lane >> 5;
    const int xorb = l31 & 7;

    // [buf][K|V][64*128 shorts]: 4 x (16KB + 16KB) = 128 KB
    __shared__ __align__(16) short KV[4][2][64 * 128];

    // Q B-frags: q = l31, step dk covers k = dk*16 + hi*8 + j
    const short* Qrow = Q + ((size_t)h * STOT + qb * 256 + wid * 32 + l31) * 128;
    bf16x8 qf[8];
#pragma unroll
    for (int dk = 0; dk < 8; ++dk)
        qf[dk] = *(const bf16x8*)(Qrow + dk * 16 + hi * 8);

    f32x16 o[4];
#pragma unroll
    for (int nt = 0; nt < 4; ++nt)
#pragma unroll
        for (int r = 0; r < 16; ++r) o[nt][r] = 0.f;
    float m = -1e30f, den = 0.f;   // per q = l31 (both hi lanes identical)

    const short* Kh = Kb + (size_t)h * STOT * 128;
    const short* Vh = VT + (size_t)h * 128 * STOT;

    // staging sources (chunk i: slot p = t + i*512), per-lane, tile 0 base
    const short* Ksrc[2]; const short* Vsrc[2];
#pragma unroll
    for (int i = 0; i < 2; ++i) {
        int p = t + i * 512;
        int krow = p >> 4, kx = (p & 15) ^ (krow & 7);
        Ksrc[i] = Kh + (size_t)krow * 128 + kx * 8;
        int vrow = p >> 3, vx = (p & 7) ^ (vrow & 7);
        Vsrc[i] = Vh + (size_t)vrow * STOT + vx * 8;
    }

    auto STAGE = [&](int b, int kb) {
#pragma unroll
        for (int i = 0; i < 2; ++i) {
            gload_lds16(Ksrc[i] + (size_t)kb * 8192, &KV[b][0][i * 4096 + wid * 512]);
            gload_lds16(Vsrc[i] + (size_t)kb * 64,   &KV[b][1][i * 4096 + wid * 512]);
        }
    };

    // loop-invariant ds_read byte offsets:
    // K frag (key=l31 row): kaddr[dk] = l31*256 + ((dk*2+hi)^xorb)*16; +8192 for key 32+l31.
    // V frag (d=l31 row): vaddr[s] = l31*128 + ((s*2+hi)^xorb)*16; +nt*4096 for d=nt*32+l31.
    int kaddr[8], vaddr[4];
#pragma unroll
    for (int dk = 0; dk < 8; ++dk)
        kaddr[dk] = l31 * 256 + (((dk * 2 + hi) ^ xorb) << 4);
#pragma unroll
    for (int s = 0; s < 4; ++s)
        vaddr[s] = l31 * 128 + (((s * 2 + hi) ^ xorb) << 4);

    const char* Kb4[4] = { (const char*)&KV[0][0][0], (const char*)&KV[1][0][0],
                           (const char*)&KV[2][0][0], (const char*)&KV[3][0][0] };
    const char* Vb4[4] = { (const char*)&KV[0][1][0], (const char*)&KV[1][1][0],
                           (const char*)&KV[2][1][0], (const char*)&KV[3][1][0] };

    // QK^T for one tile -> (s0, s1) raw scores (keys 0-31, 32-63)
    auto QK = [&](const char* Ksc, f32x16& s0, f32x16& s1) {
#pragma unroll
        for (int r = 0; r < 16; ++r) { s0[r] = 0.f; s1[r] = 0.f; }
        __builtin_amdgcn_s_setprio(1);
#pragma unroll
        for (int dk = 0; dk < 8; ++dk) {
            bf16x8 kf0 = *(const bf16x8*)(Ksc + kaddr[dk]);
            bf16x8 kf1 = *(const bf16x8*)(Ksc + kaddr[dk] + 8192);
            s0 = __builtin_amdgcn_mfma_f32_32x32x16_bf16(kf0, qf[dk], s0, 0, 0, 0);
            s1 = __builtin_amdgcn_mfma_f32_32x32x16_bf16(kf1, qf[dk], s1, 0, 0, 0);
        }
        __builtin_amdgcn_s_setprio(0);
    };

    // softmax (in place on s0/s1) + PV accumulate from Vsc
    auto SMPV = [&](const char* Vsc, f32x16& s0, f32x16& s1) {
        float v = s0[0];
#pragma unroll
        for (int r = 1; r < 16; ++r) v = fmaxf(v, s0[r]);
#pragma unroll
        for (int r = 0; r < 16; ++r) v = fmaxf(v, s1[r]);
        v = fmaxf(v, __shfl_xor(v, 32));
        if (__any(v > m + DEFER_THR)) {       // wave-uniform deferred rescale
            float mn = fmaxf(m, v);
            float al = fexp2(m - mn);
            m = mn;
            den *= al;
#pragma unroll
            for (int nt = 0; nt < 4; ++nt)
#pragma unroll
                for (int r = 0; r < 16; ++r) o[nt][r] *= al;
        }
        float rs = 0.f;
#pragma unroll
        for (int r = 0; r < 16; ++r) { s0[r] = fexp2(s0[r] - m); rs += s0[r]; }
#pragma unroll
        for (int r = 0; r < 16; ++r) { s1[r] = fexp2(s1[r] - m); rs += s1[r]; }
        rs += __shfl_xor(rs, 32);
        den += rs;

        __builtin_amdgcn_s_setprio(1);
#pragma unroll
        for (int s = 0; s < 4; ++s) {
            const f32x16& pe = (s < 2) ? s0 : s1;   // static (s unrolled)
            const int rb = (s & 1) * 8;
            uint32_t a0 = cvt_pk_bf16(pe[rb + 0], pe[rb + 1]);
            uint32_t a1 = cvt_pk_bf16(pe[rb + 2], pe[rb + 3]);
            uint32_t a2 = cvt_pk_bf16(pe[rb + 4], pe[rb + 5]);
            uint32_t a3 = cvt_pk_bf16(pe[rb + 6], pe[rb + 7]);
            permlane32_swap(a0, a2);
            permlane32_swap(a1, a3);
            union { uint32_t u[4]; bf16x8 v8; } pb;
            pb.u[0] = a0; pb.u[1] = a1; pb.u[2] = a2; pb.u[3] = a3;
#pragma unroll
            for (int nt = 0; nt < 4; ++nt) {
                bf16x8 vf = *(const bf16x8*)(Vsc + vaddr[s] + nt * 4096);
                o[nt] = __builtin_amdgcn_mfma_f32_32x32x16_bf16(vf, pb.v8, o[nt], 0, 0, 0);
            }
        }
        __builtin_amdgcn_s_setprio(0);
    };

    f32x16 scA0, scA1, scB0, scB1;

    // prologue: stage tiles 0,1; QK(0) -> scA
    STAGE(0, 0);
    STAGE(1, 1);
    asm volatile("s_waitcnt vmcnt(4)" ::: "memory");  // own tile-0 loads done
    __builtin_amdgcn_s_barrier();                      // all waves' tile-0 done
    QK(Kb4[0], scA0, scA1);

    // main loop: iter j: STAGE(j+2); vmcnt(4) [drains j+1]; barrier;
    //            QK(j+1) ; SMPV(j).  Period 4 (buf%4) x 2 (sc parity) -> 4.
    for (int jb = 0; jb < 68; jb += 4) {
        STAGE(2, jb + 2);
        asm volatile("s_waitcnt vmcnt(4)" ::: "memory");
        __builtin_amdgcn_s_barrier();
        QK(Kb4[1], scB0, scB1);
        SMPV(Vb4[0], scA0, scA1);

        STAGE(3, jb + 3);
        asm volatile("s_waitcnt vmcnt(4)" ::: "memory");
        __builtin_amdgcn_s_barrier();
        QK(Kb4[2], scA0, scA1);
        SMPV(Vb4[1], scB0, scB1);

        STAGE(0, jb + 4);
        asm volatile("s_waitcnt vmcnt(4)" ::: "memory");
        __builtin_amdgcn_s_barrier();
        QK(Kb4[3], scB0, scB1);
        SMPV(Vb4[2], scA0, scA1);

        STAGE(1, jb + 5);
        asm volatile("s_waitcnt vmcnt(4)" ::: "memory");
        __builtin_amdgcn_s_barrier();
        QK(Kb4[0], scA0, scA1);
        SMPV(Vb4[3], scB0, scB1);
    }
    // tail: j = 68 (stage 70), 69 (stage 71), 70 (no stage), 71 (no QK)
    STAGE(2, 70);
    asm volatile("s_waitcnt vmcnt(4)" ::: "memory");
    __builtin_amdgcn_s_barrier();
    QK(Kb4[1], scB0, scB1);
    SMPV(Vb4[0], scA0, scA1);

    STAGE(3, 71);
    asm volatile("s_waitcnt vmcnt(4)" ::: "memory");
    __builtin_amdgcn_s_barrier();
    QK(Kb4[2], scA0, scA1);
    SMPV(Vb4[1], scB0, scB1);

    asm volatile("s_waitcnt vmcnt(0)" ::: "memory");   // drain STAGE(71)
    __builtin_amdgcn_s_barrier();
    QK(Kb4[3], scB0, scB1);
    SMPV(Vb4[2], scA0, scA1);

    SMPV(Vb4[3], scB0, scB1);                          // j=71: no QK, no barrier

    // epilogue: q = l31; d = nt*32 + g*8 + hi*4 + (0..3) per s16x4 store
    const int qrow = qb * 256 + wid * 32 + l31;
    float inv = 1.0f / den;
    short* Orow = O + (size_t)qrow * HIDDEN + h * 128;
#pragma unroll
    for (int nt = 0; nt < 4; ++nt) {
#pragma unroll
        for (int g = 0; g < 4; ++g) {
            s16x4 w4;
#pragma unroll
            for (int j = 0; j < 4; ++j) w4[j] = f2b(o[nt][g * 4 + j] * inv);
            *(s16x4*)(Orow + nt * 32 + g * 8 + hi * 4) = w4;
        }
    }
}

// ---------------------------------------------------------------------------
extern "C" void kernel_launch(void* const* d_in, const int* in_sizes, int n_in,
                              void* d_out, int out_size, void* d_ws, size_t ws_size,
                              hipStream_t stream)
{
    (void)in_sizes; (void)n_in; (void)out_size; (void)ws_size;
    const float* txt  = (const float*)d_in[0];
    const float* img  = (const float*)d_in[1];
    const float* rope = (const float*)d_in[2];
    const float* Wtq  = (const float*)d_in[3];
    const float* Wiq  = (const float*)d_in[4];
    const float* Wto  = (const float*)d_in[5];
    const float* Wio  = (const float*)d_in[6];
    float* out = (float*)d_out;

    short* w = (short*)d_ws;
    size_t off = 0;
    auto alloc = [&](size_t elems) { short* p = w + off; off += elems; return p; };
    short* txtb = alloc((size_t)LTXT * HIDDEN);   // txtb..Wiob contiguous = cast6 dst
    short* imgb = alloc((size_t)NIMG * HIDDEN);
    short* Wtqb = alloc((size_t)QKV3 * HIDDEN);
    short* Wiqb = alloc((size_t)QKV3 * HIDDEN);
    short* Wtob = alloc((size_t)HIDDEN * HIDDEN);
    short* Wiob = alloc((size_t)HIDDEN * HIDDEN);
    short* Yt   = alloc((size_t)LTXT * QKV3);     // Yt||Yi = Y[4608][4608]
    short* Yi   = alloc((size_t)NIMG * QKV3);
    short* Qb   = alloc((size_t)NUM_HEADS * STOT * HEAD_DIM);
    short* Kb   = alloc((size_t)NUM_HEADS * STOT * HEAD_DIM);
    short* VTb  = alloc((size_t)NUM_HEADS * STOT * HEAD_DIM);
    (void)imgb; (void)Yi;
    short* Ob   = txtb;  // txtb+imgb = 4608*1536, dead after QKV GEMM

    cast6<<<12672, 256, 0, stream>>>(txt, img, Wtq, Wiq, Wto, Wio, txtb);

    // fused QKV projection: rows 0..511 use Wtq, 512.. use Wiq
    gemm_bt2<short><<<1296, 256, 0, stream>>>(
        txtb, Wtqb, Wiqb, Yt, STOT, QKV3, HIDDEN, LTXT, QKV3 / 128);

    pack_qkv<<<dim3(STOT / 64, NUM_HEADS), 256, 0, stream>>>(
        Yt, rope, Qb, Kb, VTb);

    attn_fwd<<<dim3(STOT / 256 * NUM_HEADS), 512, 0, stream>>>(Qb, Kb, VTb, Ob);

    // fused out projection: flat grid 36x12 = 432 = 8*54
    gemm_bt2<float><<<432, 256, 0, stream>>>(
        Ob, Wtob, Wiob, out, STOT, HIDDEN, HIDDEN, LTXT, HIDDEN / 128);
}